// Round 5
// baseline (192.401 us; speedup 1.0000x reference)
//
#include <hip/hip_runtime.h>

// Problem constants: B=8, S=512, D_MODEL=1024, H=16, dh=64, SCALE=8.
typedef unsigned short u16;
typedef __bf16 bf16_t;
typedef bf16_t bf16x8 __attribute__((ext_vector_type(8)));
typedef float f32x4 __attribute__((ext_vector_type(4)));
typedef u16 u16x8 __attribute__((ext_vector_type(8)));
typedef u16 u16x4 __attribute__((ext_vector_type(4)));

__device__ __forceinline__ u16 f2b(float f) {
    unsigned int u = __float_as_uint(f);
    u += 0x7fffu + ((u >> 16) & 1u);   // RNE
    return (u16)(u >> 16);
}

__device__ __forceinline__ f32x4 mfma16(u16x8 a, u16x8 b, f32x4 c) {
    return __builtin_amdgcn_mfma_f32_16x16x32_bf16(
        __builtin_bit_cast(bf16x8, a), __builtin_bit_cast(bf16x8, b), c, 0, 0, 0);
}

#define GLDS16(gp, lp)                                                          \
    __builtin_amdgcn_global_load_lds(                                           \
        (const __attribute__((address_space(1))) void*)(gp),                    \
        (__attribute__((address_space(3))) void*)(lp), 16, 0, 0)

// ---------------- fp32 -> bf16 convert (x | Wqkv | fc_w fused) ---------------
__global__ __launch_bounds__(256) void cvt3_kernel(const float* __restrict__ s0,
                                                   const float* __restrict__ s1,
                                                   const float* __restrict__ s2,
                                                   u16* __restrict__ d0,
                                                   u16* __restrict__ d1,
                                                   u16* __restrict__ d2) {
    int i = (blockIdx.x * 256 + threadIdx.x) * 4;   // block-uniform ranges
    const float* src; u16* dst;
    if (i < 4194304)       { src = s0;           dst = d0;           }
    else if (i < 8388608)  { src = s1 - 4194304; dst = d1 - 4194304; }
    else                   { src = s2 - 8388608; dst = d2 - 8388608; }
    float4 f = *(const float4*)(src + i);
    u16x4 o = { f2b(f.x), f2b(f.y), f2b(f.z), f2b(f.w) };
    *(u16x4*)(dst + i) = o;
}

// ---------------- QKV GEMM: 128x128 tile, BK=32, 4-ring LDS, counted vmcnt ---
// R5: back to 128^2 tiles. R1-R3 proved the 256^2 1-block/CU structure is
// schedule-invariant at 3225 cyc/tile (MfmaUtil 29%, Occupancy 16%): with
// 128 KB LDS there is exactly 1 block/CU, all 8 waves share every barrier,
// and nothing fills the stall windows. The measured ladder (m103/m112/m114)
// says at the simple-loop structure 128^2 + ~2-3 blocks/CU wins (912 vs 792
// TF): cross-BLOCK overlap (independent barriers) fills the gaps.
// Geometry: 256 thr = 4 waves (wm=w>>1, wn=w&1), wave-out 64x64 = acc[4][4].
// Ring-4 LDS = 4 x (A 128x32 + B 128x32) u16 = 64 KB -> 2 blocks/CU resident.
// Per K-tile: {stage 4 gload_lds for t+3 | 8 ds_read_b128 | 16 MFMA |
// vmcnt(8) | barrier}. Tail peeled 8->4->0. Chunk-XOR swizzle (proven 0
// bank conflicts): chunk c of row r stored at c ^ ((r>>1)&3), applied as
// inverse-swizzled GLOBAL source + swizzled ds_read offset.
// Grid 1024 = 32x32 tiles; per-XCD 16x8 rectangle (working set 6 MB/XCD).
__global__ __launch_bounds__(256, 2) void gemm128_qkv(
    const u16* __restrict__ A, const u16* __restrict__ Bw,
    u16* __restrict__ Qf, u16* __restrict__ K1f,
    u16* __restrict__ K2f, u16* __restrict__ Vf)
{
    __shared__ u16 lds[4][2][4096];   // [ring][A=0/B=1][128 rows x 32 cols] = 64 KB

    const int t = threadIdx.x;        // 0..255
    const int lane = t & 63;
    const int w = t >> 6;             // 0..3
    const int wm = w >> 1, wn = w & 1;
    const int lr = lane & 15, quad = lane >> 4;

    // XCD-aware bijective mapping: 1024 blocks, XCD k owns a 16(bx) x 8(by)
    // rectangle of the 32x32 tile grid.
    const int lin = blockIdx.x;
    const int xcd = lin & 7, j = lin >> 3;            // j 0..127
    const int bx = (xcd & 1) * 16 + (j & 15);
    const int by = (xcd >> 1) * 8 + (j >> 4);
    const int tileM = by * 128, tileN = bx * 128;

    // staging: thread t covers slots s = t and t+256 of each 512-slot region;
    // slot s: row = s>>2, chunkpos = s&3; source fetches the chunk the
    // swizzled READ expects there: c_g = (s&3) ^ ((row>>1)&3) = (t&3)^((t>>3)&3)
    // (identical for s=t+256 since row offset 64 == 0 mod 4 after >>1).
    const int scol = ((t & 3) ^ ((t >> 3) & 3)) * 8;
    const u16* Asrc0 = A + (size_t)(tileM + (t >> 2)) * 1024 + scol;
    const u16* Asrc1 = Asrc0 + (size_t)64 * 1024;
    const u16* Bsrc0 = Bw + (size_t)(tileN + (t >> 2)) * 1024 + scol;
    const u16* Bsrc1 = Bsrc0 + (size_t)64 * 1024;

    // swizzled ds_read offsets (u16 units); read row = base16 + lr, and all
    // base16 terms are 0 mod 8, so (row>>1)&3 = (lr>>1)&3.
    const int swzq = (quad ^ ((lr >> 1) & 3)) * 8;
    const int aoff = (wm * 64 + lr) * 32 + swzq;    // + mi*512
    const int boff = (wn * 64 + lr) * 32 + swzq;    // + ni*512

    f32x4 acc[4][4] = {};

#define STAGE_A(tk, buf)                                                        \
    do { GLDS16(Asrc0 + (tk) * 32, &lds[buf][0][t * 8]);                        \
         GLDS16(Asrc1 + (tk) * 32, &lds[buf][0][(t + 256) * 8]); } while (0)
#define STAGE_B(tk, buf)                                                        \
    do { GLDS16(Bsrc0 + (tk) * 32, &lds[buf][1][t * 8]);                        \
         GLDS16(Bsrc1 + (tk) * 32, &lds[buf][1][(t + 256) * 8]); } while (0)

#define DO_TILE(tk, DO_ST, VMASM)                                               \
    do {                                                                        \
        const int cur_ = (tk) & 3, nxt_ = ((tk) + 3) & 3;                       \
        const u16* aL = &lds[cur_][0][0];                                       \
        const u16* bL = &lds[cur_][1][0];                                       \
        if (DO_ST) { STAGE_A((tk) + 3, nxt_); STAGE_B((tk) + 3, nxt_); }        \
        u16x8 af[4], bf[4];                                                     \
        _Pragma("unroll") for (int i = 0; i < 4; ++i)                           \
            af[i] = *(const u16x8*)(aL + aoff + i * 512);                       \
        _Pragma("unroll") for (int i = 0; i < 4; ++i)                           \
            bf[i] = *(const u16x8*)(bL + boff + i * 512);                       \
        __builtin_amdgcn_s_setprio(1);                                          \
        _Pragma("unroll") for (int mi = 0; mi < 4; ++mi)                        \
            _Pragma("unroll") for (int ni = 0; ni < 4; ++ni)                    \
                acc[mi][ni] = mfma16(af[mi], bf[ni], acc[mi][ni]);              \
        __builtin_amdgcn_s_setprio(0);                                          \
        VMASM;                                                                  \
        __builtin_amdgcn_s_barrier();                                           \
    } while (0)

    // prologue: tiles 0,1,2 in flight; wait for tile 0 only (8 newer may remain)
    STAGE_A(0, 0); STAGE_B(0, 0);
    STAGE_A(1, 1); STAGE_B(1, 1);
    STAGE_A(2, 2); STAGE_B(2, 2);
    asm volatile("s_waitcnt vmcnt(8)" ::: "memory");
    __builtin_amdgcn_s_barrier();

#pragma unroll 4
    for (int tk = 0; tk < 28; ++tk)
        DO_TILE(tk, true, asm volatile("s_waitcnt vmcnt(8)" ::: "memory"));
    DO_TILE(28, true,  asm volatile("s_waitcnt vmcnt(8)" ::: "memory"));
    DO_TILE(29, false, asm volatile("s_waitcnt vmcnt(4)" ::: "memory"));
    DO_TILE(30, false, asm volatile("s_waitcnt vmcnt(0)" ::: "memory"));
    DO_TILE(31, false, (void)0);
#undef DO_TILE
#undef STAGE_A
#undef STAGE_B

    // ---------------- epilogue: frag-major scatter (R0-proven, 4-wave) -------
#pragma unroll
    for (int mi = 0; mi < 4; ++mi)
#pragma unroll
        for (int ni = 0; ni < 4; ++ni) {
            int n = tileN + wn * 64 + ni * 16 + lr;
            int kv = n >> 10;                 // 0=q 1=k1 2=k2 3=v
            int h = (n >> 6) & 15, d = n & 63;
#pragma unroll
            for (int r = 0; r < 4; ++r) {
                int m = tileM + wm * 64 + mi * 16 + quad * 4 + r;
                int s = m & 511, bh = ((m >> 9) << 4) + h;
                u16 v = f2b(acc[mi][ni][r]);
                if (kv < 3) {
                    u16* base = (kv == 0) ? Qf : (kv == 1) ? K1f : K2f;
                    size_t idx = ((size_t)((bh * 32 + (s >> 4)) * 2 + (d >> 5))) * 512
                               + (((d >> 3) & 3) * 16 + (s & 15)) * 8 + (d & 7);
                    base[idx] = v;
                } else {
                    size_t idx = ((size_t)((bh * 4 + (d >> 4)) * 16 + (s >> 5))) * 512
                               + (((s >> 3) & 3) * 16 + (d & 15)) * 8 + (s & 7);
                    Vf[idx] = v;
                }
            }
        }
}

// ---------------- NT bf16 GEMM, K=1024, double-buffered LDS (proj only) ------
// MODE 1 (MT=64):  Cf[m][n] = acc + bias[n]  (fp32, ld 1024)
template <int MT, int MODE>
__global__ __launch_bounds__(256) void gemm_bt(
    const u16* __restrict__ A, const u16* __restrict__ Bw,
    u16* __restrict__ Qf, u16* __restrict__ K1f,
    u16* __restrict__ K2f, u16* __restrict__ Vf,
    float* __restrict__ Cf, const float* __restrict__ biasp)
{
    constexpr int K = 1024;
    constexpr int MF = MT / 32;            // A-frags per wave (4 or 2)
    __shared__ u16 As[2][MT * 32];
    __shared__ u16 Bs[2][128 * 32];
    const int t = threadIdx.x;
    const int lane = t & 63;
    const int w = t >> 6;
    const int wm = w >> 1, wn = w & 1;
    const int lr = lane & 15, quad = lane >> 4;
    const int tileM = blockIdx.y * MT, tileN = blockIdx.x * 128;

    f32x4 acc[MF][4] = {};

    const u16* Ag = A + (size_t)(tileM + (t >> 2)) * K + (t & 3) * 8;
    const u16* Bg = Bw + (size_t)(tileN + (t >> 2)) * K + (t & 3) * 8;

#define STAGE(kk, bufi)                                                         \
    do {                                                                        \
        GLDS16(Ag + (kk), &As[bufi][t * 8]);                                    \
        if (MT == 128) GLDS16(Ag + (kk) + 64 * K, &As[bufi][t * 8 + 2048]);     \
        GLDS16(Bg + (kk), &Bs[bufi][t * 8]);                                    \
        GLDS16(Bg + (kk) + 64 * K, &Bs[bufi][t * 8 + 2048]);                    \
    } while (0)

    STAGE(0, 0);
    __syncthreads();

#pragma unroll 2
    for (int kk = 0; kk < K; kk += 32) {
        const int cur = (kk >> 5) & 1;
        if (kk + 32 < K) STAGE(kk + 32, cur ^ 1);   // prefetch next tile

        u16x8 af[MF], bf[4];
#pragma unroll
        for (int i = 0; i < MF; ++i)
            af[i] = *(const u16x8*)(&As[cur][(wm * (MT / 2) + i * 16 + lr) * 32 + quad * 8]);
#pragma unroll
        for (int i = 0; i < 4; ++i)
            bf[i] = *(const u16x8*)(&Bs[cur][(wn * 64 + i * 16 + lr) * 32 + quad * 8]);
#pragma unroll
        for (int mi = 0; mi < MF; ++mi)
#pragma unroll
            for (int ni = 0; ni < 4; ++ni)
                acc[mi][ni] = mfma16(af[mi], bf[ni], acc[mi][ni]);

        __syncthreads();   // drains prefetch vmcnt + protects buffer reuse
    }
#undef STAGE

    if (MODE == 0) {
#pragma unroll
        for (int mi = 0; mi < MF; ++mi)
#pragma unroll
            for (int ni = 0; ni < 4; ++ni) {
                int n = tileN + wn * 64 + ni * 16 + lr;
                int kv = n >> 10;                 // 0=q 1=k1 2=k2 3=v
                int h = (n >> 6) & 15, d = n & 63;
#pragma unroll
                for (int r = 0; r < 4; ++r) {
                    int m = tileM + wm * (MT / 2) + mi * 16 + quad * 4 + r;
                    int s = m & 511, bh = ((m >> 9) << 4) + h;
                    u16 v = f2b(acc[mi][ni][r]);
                    if (kv < 3) {
                        u16* base = (kv == 0) ? Qf : (kv == 1) ? K1f : K2f;
                        size_t idx = ((size_t)((bh * 32 + (s >> 4)) * 2 + (d >> 5))) * 512
                                   + (((d >> 3) & 3) * 16 + (s & 15)) * 8 + (d & 7);
                        base[idx] = v;
                    } else {
                        size_t idx = ((size_t)((bh * 4 + (d >> 4)) * 16 + (s >> 5))) * 512
                                   + (((s >> 3) & 3) * 16 + (d & 15)) * 8 + (s & 7);
                        Vf[idx] = v;
                    }
                }
            }
    } else {
#pragma unroll
        for (int mi = 0; mi < MF; ++mi)
#pragma unroll
            for (int ni = 0; ni < 4; ++ni) {
                int n = tileN + wn * 64 + ni * 16 + lr;
                float bv = biasp[n];
#pragma unroll
                for (int r = 0; r < 4; ++r) {
                    int m = tileM + wm * (MT / 2) + mi * 16 + quad * 4 + r;
                    Cf[(size_t)m * 1024 + n] = acc[mi][ni][r] + bv;
                }
            }
    }
}

// ---------------- attention: flash-style, 2 q-groups per block ---------------
__global__ __launch_bounds__(256, 2) void attn_kernel(
    const u16* __restrict__ qfm, const u16* __restrict__ k1fm,
    const u16* __restrict__ k2fm, const u16* __restrict__ vfm,
    const int* __restrict__ maskp, const int* __restrict__ qmaskp,
    const float* __restrict__ shiftp, const float* __restrict__ biasp,
    u16* __restrict__ ao)
{
    __shared__ u16 Ks[2][2][2][2][512];  // [buf][kv][t01][kh][lane*8]  16 KB
    __shared__ u16 Vs[2][4][512];        // [buf][ot][lane*8]            8 KB
    __shared__ u16 Pw[4][2][512];        // [wave][group][...]           8 KB

    const int bh = blockIdx.x & 127, qh = blockIdx.x >> 7;
    const int b = bh >> 4;
    const int t = threadIdx.x, lane = t & 63, w = t >> 6;
    const int lr = lane & 15, quad = lane >> 4;
    const float shiftv = shiftp[0], biasv = biasp[0];

    const int m16a = qh * 8 + w;         // group a 16-row q block
    const int m16b = m16a + 4;           // group b
    const int qbaseA = m16a * 16;
    const int qbaseB = m16b * 16;

    const u16* qsrcA = qfm + ((size_t)(bh * 32 + m16a) * 2) * 512 + lane * 8;
    const u16* qsrcB = qfm + ((size_t)(bh * 32 + m16b) * 2) * 512 + lane * 8;
    u16x8 qa0 = *(const u16x8*)(qsrcA);
    u16x8 qa1 = *(const u16x8*)(qsrcA + 512);
    u16x8 qb0 = *(const u16x8*)(qsrcB);
    u16x8 qb1 = *(const u16x8*)(qsrcB + 512);

    int qmrA[4], qmrB[4]; float rowfA[4], rowfB[4];
#pragma unroll
    for (int r = 0; r < 4; ++r) {
        int ma = qbaseA + quad * 4 + r;
        int mb = qbaseB + quad * 4 + r;
        qmrA[r] = qmaskp[b * 512 + ma];
        qmrB[r] = qmaskp[b * 512 + mb];
        rowfA[r] = (float)ma;
        rowfB[r] = (float)mb;
    }

    f32x4 oa0 = {0,0,0,0}, oa1 = {0,0,0,0}, oa2 = {0,0,0,0}, oa3 = {0,0,0,0};
    f32x4 ob0 = {0,0,0,0}, ob1 = {0,0,0,0}, ob2 = {0,0,0,0}, ob3 = {0,0,0,0};
    float lsa[4] = {0,0,0,0}, lsb[4] = {0,0,0,0};

    u16* pbA = &Pw[w][0][0];
    u16* pbB = &Pw[w][1][0];
    const int wa0 = quad * 128 + (((lr >> 3) ^ quad) * 8) + (lr & 7);
    const int wa1 = quad * 128 + (((2 | (lr >> 3)) ^ quad) * 8) + (lr & 7);
    const int ra = lr * 32 + ((quad ^ (lr >> 2)) * 8);

    const int s_ = w >> 1, kh_ = w & 1;
    const u16* k1s = k1fm + ((size_t)(bh * 32 + s_) * 2 + kh_) * 512 + lane * 8;
    const u16* k2s = k2fm + ((size_t)(bh * 32 + s_) * 2 + kh_) * 512 + lane * 8;
    const u16* vsrc = vfm + ((size_t)(bh * 4 + w) * 16) * 512 + lane * 8;

#define ASTAGE(cc, bufi)                                                        \
    do {                                                                        \
        GLDS16(k1s + (size_t)(cc) * 2048, &Ks[bufi][0][s_][kh_][lane * 8]);     \
        GLDS16(k2s + (size_t)(cc) * 2048, &Ks[bufi][1][s_][kh_][lane * 8]);     \
        GLDS16(vsrc + (size_t)(cc) * 512, &Vs[bufi][w][lane * 8]);              \
    } while (0)

    const int* qmb = qmaskp + b * 512;
    const int* kmb = maskp + b * 512;

    ASTAGE(0, 0);
    __syncthreads();

    for (int cc = 0; cc < 16; ++cc) {
        const int cur = cc & 1;
        if (cc < 15) ASTAGE(cc + 1, cur ^ 1);

        u16x8 k1t0a = *(const u16x8*)(&Ks[cur][0][0][0][lane * 8]);
        u16x8 k1t0b = *(const u16x8*)(&Ks[cur][0][0][1][lane * 8]);
        u16x8 k1t1a = *(const u16x8*)(&Ks[cur][0][1][0][lane * 8]);
        u16x8 k1t1b = *(const u16x8*)(&Ks[cur][0][1][1][lane * 8]);
        u16x8 k2t0a = *(const u16x8*)(&Ks[cur][1][0][0][lane * 8]);
        u16x8 k2t0b = *(const u16x8*)(&Ks[cur][1][0][1][lane * 8]);
        u16x8 k2t1a = *(const u16x8*)(&Ks[cur][1][1][0][lane * 8]);
        u16x8 k2t1b = *(const u16x8*)(&Ks[cur][1][1][1][lane * 8]);

        f32x4 z = {0.f, 0.f, 0.f, 0.f};
        f32x4 sa1t0 = mfma16(qa1, k1t0b, mfma16(qa0, k1t0a, z));
        f32x4 sa2t0 = mfma16(qa1, k2t0b, mfma16(qa0, k2t0a, z));
        f32x4 sa1t1 = mfma16(qa1, k1t1b, mfma16(qa0, k1t1a, z));
        f32x4 sa2t1 = mfma16(qa1, k2t1b, mfma16(qa0, k2t1a, z));
        f32x4 sb1t0 = mfma16(qb1, k1t0b, mfma16(qb0, k1t0a, z));
        f32x4 sb2t0 = mfma16(qb1, k2t0b, mfma16(qb0, k2t0a, z));
        f32x4 sb1t1 = mfma16(qb1, k1t1b, mfma16(qb0, k1t1a, z));
        f32x4 sb2t1 = mfma16(qb1, k2t1b, mfma16(qb0, k2t1a, z));

        const int col0 = cc * 32 + lr, col1 = col0 + 16;
        const int qmc0 = qmb[col0], qmc1 = qmb[col1];
        const float ka0 = (kmb[col0] ? 0.f : -1e30f) - 10.0f;
        const float ka1 = (kmb[col1] ? 0.f : -1e30f) - 10.0f;
        const float colf0 = (float)col0, colf1 = (float)col1;

        u16x8 vf0 = *(const u16x8*)(&Vs[cur][0][lane * 8]);
        u16x8 vf1 = *(const u16x8*)(&Vs[cur][1][lane * 8]);
        u16x8 vf2 = *(const u16x8*)(&Vs[cur][2][lane * 8]);
        u16x8 vf3 = *(const u16x8*)(&Vs[cur][3][lane * 8]);

        {
            float p0[4], p1[4];
#pragma unroll
            for (int r = 0; r < 4; ++r) {
                float d0 = rowfA[r] - colf0;
                float d1 = rowfA[r] - colf1;
                float sel0 = (qmrA[r] == qmc0) ? sa1t0[r] : sa2t0[r];
                float sel1 = (qmrA[r] == qmc1) ? sa1t1[r] : sa2t1[r];
                float v0 = fmaf(sel0, 0.125f, -fmaf(shiftv * d0, d0, biasv)) + ka0;
                float v1 = fmaf(sel1, 0.125f, -fmaf(shiftv * d1, d1, biasv)) + ka1;
                p0[r] = __expf(v0);
                p1[r] = __expf(v1);
                lsa[r] += p0[r] + p1[r];
            }
#pragma unroll
            for (int r = 0; r < 4; ++r) {
                pbA[wa0 + r * 32] = f2b(p0[r]);
                pbA[wa1 + r * 32] = f2b(p1[r]);
            }
            u16x8 af = *(const u16x8*)(pbA + ra);   // same-wave RAW; lgkmcnt only
            oa0 = mfma16(af, vf0, oa0);
            oa1 = mfma16(af, vf1, oa1);
            oa2 = mfma16(af, vf2, oa2);
            oa3 = mfma16(af, vf3, oa3);
        }
        {
            float p0[4], p1[4];
#pragma unroll
            for (int r = 0; r < 4; ++r) {
                float d0 = rowfB[r] - colf0;
                float d1 = rowfB[r] - colf1;
                float sel0 = (qmrB[r] == qmc0) ? sb1t0[r] : sb2t0[r];
                float sel1 = (qmrB[r] == qmc1) ? sb1t1[r] : sb2t1[r];
                float v0 = fmaf(sel0, 0.125f, -fmaf(shiftv * d0, d0, biasv)) + ka0;
                float v1 = fmaf(sel1, 0.125f, -fmaf(shiftv * d1, d1, biasv)) + ka1;
                p0[r] = __expf(v0);
                p1[r] = __expf(v1);
                lsb[r] += p0[r] + p1[r];
            }
#pragma unroll
            for (int r = 0; r < 4; ++r) {
                pbB[wa0 + r * 32] = f2b(p0[r]);
                pbB[wa1 + r * 32] = f2b(p1[r]);
            }
            u16x8 af = *(const u16x8*)(pbB + ra);
            ob0 = mfma16(af, vf0, ob0);
            ob1 = mfma16(af, vf1, ob1);
            ob2 = mfma16(af, vf2, ob2);
            ob3 = mfma16(af, vf3, ob3);
        }

        __syncthreads();
    }
#undef ASTAGE

#pragma unroll
    for (int r = 0; r < 4; ++r) {
        float s = lsa[r];
#pragma unroll
        for (int m = 1; m < 16; m <<= 1) s += __shfl_xor(s, m);
        float inv = 1.0f / s;
        int grow = b * 512 + qbaseA + quad * 4 + r;
        u16* orow = ao + (size_t)grow * 1024 + (bh & 15) * 64 + lr;
        orow[0]  = f2b(oa0[r] * inv);
        orow[16] = f2b(oa1[r] * inv);
        orow[32] = f2b(oa2[r] * inv);
        orow[48] = f2b(oa3[r] * inv);
    }
#pragma unroll
    for (int r = 0; r < 4; ++r) {
        float s = lsb[r];
#pragma unroll
        for (int m = 1; m < 16; m <<= 1) s += __shfl_xor(s, m);
        float inv = 1.0f / s;
        int grow = b * 512 + qbaseB + quad * 4 + r;
        u16* orow = ao + (size_t)grow * 1024 + (bh & 15) * 64 + lr;
        orow[0]  = f2b(ob0[r] * inv);
        orow[16] = f2b(ob1[r] * inv);
        orow[32] = f2b(ob2[r] * inv);
        orow[48] = f2b(ob3[r] * inv);
    }
}

extern "C" void kernel_launch(void* const* d_in, const int* in_sizes, int n_in,
                              void* d_out, int out_size, void* d_ws, size_t ws_size,
                              hipStream_t stream) {
    (void)in_sizes; (void)n_in; (void)out_size; (void)ws_size;
    const float* x      = (const float*)d_in[0];
    const int*   maskp  = (const int*)d_in[1];
    const int*   qmaskp = (const int*)d_in[2];
    const float* Wqkv   = (const float*)d_in[3];
    const float* fc_w   = (const float*)d_in[4];
    const float* fc_b   = (const float*)d_in[5];
    const float* shiftp = (const float*)d_in[6];
    const float* biasp  = (const float*)d_in[7];
    float* out = (float*)d_out;

    char* ws = (char*)d_ws;
    u16* xb   = (u16*)(ws);                      //  8 MB: x bf16 [4096,1024]
    u16* wb   = (u16*)(ws + (8u << 20));         //  8 MB: Wqkv bf16 [4096,1024]
    u16* fwb  = (u16*)(ws + (16u << 20));        //  2 MB: fc_w bf16 [1024,1024]
    u16* qfm  = (u16*)(ws + (18u << 20));        //  8 MB: q frag-major
    u16* k1fm = (u16*)(ws + (26u << 20));        //  8 MB: k1 frag-major
    u16* k2fm = (u16*)(ws + (34u << 20));        //  8 MB: k2 frag-major
    u16* vfm  = (u16*)(ws + (42u << 20));        //  8 MB: v frag-major
    u16* aob  = (u16*)(ws + (50u << 20));        //  8 MB: attn out bf16 [4096,1024]

    cvt3_kernel<<<9216, 256, 0, stream>>>(x, Wqkv, fc_w, xb, wb, fwb);
    gemm128_qkv<<<1024, 256, 0, stream>>>(xb, wb, qfm, k1fm, k2fm, vfm);
    attn_kernel<<<512, 256, 0, stream>>>(qfm, k1fm, k2fm, vfm, maskp, qmaskp,
                                         shiftp, biasp, aob);
    gemm_bt<64, 1><<<dim3(8, 64), 256, 0, stream>>>(aob, fwb, nullptr, nullptr,
                                                    nullptr, nullptr, out, fc_b);
}

// Round 6
// 173.821 us; speedup vs baseline: 1.1069x; 1.1069x over previous
//
#include <hip/hip_runtime.h>

// Problem constants: B=8, S=512, D_MODEL=1024, H=16, dh=64, SCALE=8.
typedef unsigned short u16;
typedef __bf16 bf16_t;
typedef bf16_t bf16x8 __attribute__((ext_vector_type(8)));
typedef float f32x4 __attribute__((ext_vector_type(4)));
typedef u16 u16x8 __attribute__((ext_vector_type(8)));
typedef u16 u16x4 __attribute__((ext_vector_type(4)));

__device__ __forceinline__ u16 f2b(float f) {
    unsigned int u = __float_as_uint(f);
    u += 0x7fffu + ((u >> 16) & 1u);   // RNE
    return (u16)(u >> 16);
}

__device__ __forceinline__ f32x4 mfma16(u16x8 a, u16x8 b, f32x4 c) {
    return __builtin_amdgcn_mfma_f32_16x16x32_bf16(
        __builtin_bit_cast(bf16x8, a), __builtin_bit_cast(bf16x8, b), c, 0, 0, 0);
}

#define GLDS16(gp, lp)                                                          \
    __builtin_amdgcn_global_load_lds(                                           \
        (const __attribute__((address_space(1))) void*)(gp),                    \
        (__attribute__((address_space(3))) void*)(lp), 16, 0, 0)

// ---------------- fp32 -> bf16 convert (x | Wqkv | fc_w fused) ---------------
__global__ __launch_bounds__(256) void cvt3_kernel(const float* __restrict__ s0,
                                                   const float* __restrict__ s1,
                                                   const float* __restrict__ s2,
                                                   u16* __restrict__ d0,
                                                   u16* __restrict__ d1,
                                                   u16* __restrict__ d2) {
    int i = (blockIdx.x * 256 + threadIdx.x) * 4;   // block-uniform ranges
    const float* src; u16* dst;
    if (i < 4194304)       { src = s0;           dst = d0;           }
    else if (i < 8388608)  { src = s1 - 4194304; dst = d1 - 4194304; }
    else                   { src = s2 - 8388608; dst = d2 - 8388608; }
    float4 f = *(const float4*)(src + i);
    u16x4 o = { f2b(f.x), f2b(f.y), f2b(f.z), f2b(f.w) };
    *(u16x4*)(dst + i) = o;
}

// ---------------- QKV GEMM: 256x256 tile, BK=32, 4-ring LDS, counted vmcnt ---
// R4 version verbatim — session-best measured: 42.7-43.8 us (~800 TF).
// R1-R5 established: schedule variants (4-barrier / unpinned / 1-barrier) and
// 128^2 ring all land at or above this; MfmaUtil 29% == pure MFMA issue time.
__global__ __launch_bounds__(512, 2) void gemm256_qkv(
    const u16* __restrict__ A, const u16* __restrict__ Bw,
    u16* __restrict__ Qf, u16* __restrict__ K1f,
    u16* __restrict__ K2f, u16* __restrict__ Vf)
{
    __shared__ u16 lds[4][2][8192];   // [ring][A=0/B=1][256 rows x 32 cols] = 128 KB

    const int t = threadIdx.x;        // 0..511
    const int lane = t & 63;
    const int w = t >> 6;             // 0..7
    const int wm = w >> 2, wn = w & 3;
    const int lr = lane & 15, quad = lane >> 4;

    // XCD-aware bijective swizzle (grid 256 = 16x16, 256 % 8 == 0)
    const int lin = blockIdx.x;
    const int swz = (lin & 7) * 32 + (lin >> 3);
    const int bx = swz & 15, by = swz >> 4;
    const int tileM = by * 256, tileN = bx * 256;

    const int srow = t >> 2;
    const int scol = ((t & 3) ^ ((t >> 3) & 3)) * 8;
    const u16* Asrc0 = A + (size_t)(tileM + srow) * 1024 + scol;
    const u16* Asrc1 = Asrc0 + (size_t)128 * 1024;
    const u16* Bsrc0 = Bw + (size_t)(tileN + srow) * 1024 + scol;
    const u16* Bsrc1 = Bsrc0 + (size_t)128 * 1024;

    const int swzq = (quad ^ ((lr >> 1) & 3)) * 8;
    const int aoff = (wm * 128 + lr) * 32 + swzq;   // + mi*512
    const int boff = (wn * 64 + lr) * 32 + swzq;    // + ni*512

    f32x4 acc[8][4] = {};

#define STAGE_A(tk, buf)                                                        \
    do { GLDS16(Asrc0 + (tk) * 32, &lds[buf][0][t * 8]);                        \
         GLDS16(Asrc1 + (tk) * 32, &lds[buf][0][(t + 512) * 8]); } while (0)
#define STAGE_B(tk, buf)                                                        \
    do { GLDS16(Bsrc0 + (tk) * 32, &lds[buf][1][t * 8]);                        \
         GLDS16(Bsrc1 + (tk) * 32, &lds[buf][1][(t + 512) * 8]); } while (0)

#define DO_TILE(tk, DO_ST, VMASM)                                               \
    do {                                                                        \
        const int cur_ = (tk) & 3, nxt_ = ((tk) + 3) & 3;                       \
        const u16* aL = &lds[cur_][0][0];                                       \
        const u16* bL = &lds[cur_][1][0];                                       \
        if (DO_ST) { STAGE_A((tk) + 3, nxt_); STAGE_B((tk) + 3, nxt_); }        \
        u16x8 af[8], bf[4];                                                     \
        _Pragma("unroll") for (int i = 0; i < 4; ++i)                           \
            bf[i] = *(const u16x8*)(bL + boff + i * 512);                       \
        _Pragma("unroll") for (int i = 0; i < 8; ++i)                           \
            af[i] = *(const u16x8*)(aL + aoff + i * 512);                       \
        __builtin_amdgcn_s_setprio(1);                                          \
        _Pragma("unroll") for (int mi = 0; mi < 8; ++mi)                        \
            _Pragma("unroll") for (int ni = 0; ni < 4; ++ni)                    \
                acc[mi][ni] = mfma16(af[mi], bf[ni], acc[mi][ni]);              \
        __builtin_amdgcn_s_setprio(0);                                          \
        VMASM;                                                                  \
        __builtin_amdgcn_s_barrier();                                           \
    } while (0)

    STAGE_A(0, 0); STAGE_B(0, 0);
    STAGE_A(1, 1); STAGE_B(1, 1);
    STAGE_A(2, 2); STAGE_B(2, 2);
    asm volatile("s_waitcnt vmcnt(8)" ::: "memory");
    __builtin_amdgcn_s_barrier();

#pragma unroll 4
    for (int tk = 0; tk < 28; ++tk)
        DO_TILE(tk, true, asm volatile("s_waitcnt vmcnt(8)" ::: "memory"));
    DO_TILE(28, true,  asm volatile("s_waitcnt vmcnt(8)" ::: "memory"));
    DO_TILE(29, false, asm volatile("s_waitcnt vmcnt(4)" ::: "memory"));
    DO_TILE(30, false, asm volatile("s_waitcnt vmcnt(0)" ::: "memory"));
    DO_TILE(31, false, (void)0);
#undef DO_TILE
#undef STAGE_A
#undef STAGE_B

    const int kv = tileN >> 10;                              // block-uniform
    const int h  = ((tileN + wn * 64) >> 6) & 15;            // wave-uniform
    const int bh = (((tileM + wm * 128) >> 9) << 4) + h;     // wave-uniform
    const int M16 = ((tileM & 511) + wm * 128) >> 4;
    const int M32 = M16 >> 1;

    if (kv < 3) {
        u16* base = (kv == 0) ? Qf : (kv == 1) ? K1f : K2f;
#pragma unroll
        for (int mi = 0; mi < 8; ++mi)
#pragma unroll
            for (int ni = 0; ni < 4; ++ni) {
                size_t idx0 = ((size_t)((bh * 32 + M16 + mi) * 2 + (ni >> 1))) * 512
                            + (((ni * 2 + (lr >> 3)) & 3) * 16 + quad * 4) * 8 + (lr & 7);
#pragma unroll
                for (int r = 0; r < 4; ++r)
                    base[idx0 + r * 8] = f2b(acc[mi][ni][r]);
            }
    } else {
#pragma unroll
        for (int mi = 0; mi < 8; ++mi)
#pragma unroll
            for (int ni = 0; ni < 4; ++ni) {
                size_t idx = ((size_t)((bh * 4 + ni) * 16 + M32 + (mi >> 1))) * 512
                           + (((mi * 2 + (quad >> 1)) & 3) * 16 + lr) * 8 + (quad & 1) * 4;
                u16x4 o = { f2b(acc[mi][ni][0]), f2b(acc[mi][ni][1]),
                            f2b(acc[mi][ni][2]), f2b(acc[mi][ni][3]) };
                *(u16x4*)(Vf + idx) = o;
            }
    }
}

// ---------------- proj GEMM: 128x128 tile, BK=32, ring-4, counted vmcnt ------
// R6: replaces gemm_bt<64,1> (R0-era 2-buffer full-drain, MT=64, est 18-24 us)
// with the session's ring/counted-vmcnt 128^2 body (measured 609 TF as QKV in
// R5) + MODE-1 epilogue: Cf[m][n] = acc + bias[n], fp32 coalesced.
// M=4096, N=1024 -> 32x8 = 256 blocks = 1/CU. XCD k owns a 4(M)x8(N) rect.
__global__ __launch_bounds__(256, 2) void gemm128_proj(
    const u16* __restrict__ A, const u16* __restrict__ Bw,
    float* __restrict__ Cf, const float* __restrict__ biasp)
{
    __shared__ u16 lds[4][2][4096];   // [ring][A=0/B=1][128 rows x 32 cols] = 64 KB

    const int t = threadIdx.x;        // 0..255
    const int lane = t & 63;
    const int w = t >> 6;             // 0..3
    const int wm = w >> 1, wn = w & 1;
    const int lr = lane & 15, quad = lane >> 4;

    // XCD-aware bijective mapping: 256 blocks = 32(M) x 8(N) tiles; XCD k owns
    // M-rows k*4..k*4+3 x all 8 N (A-panel 1 MB + B 2 MB per XCD L2).
    const int lin = blockIdx.x;
    const int xcd = lin & 7, j = lin >> 3;            // j 0..31
    const int bx = j & 7;
    const int by = xcd * 4 + (j >> 3);
    const int tileM = by * 128, tileN = bx * 128;

    const int scol = ((t & 3) ^ ((t >> 3) & 3)) * 8;
    const u16* Asrc0 = A + (size_t)(tileM + (t >> 2)) * 1024 + scol;
    const u16* Asrc1 = Asrc0 + (size_t)64 * 1024;
    const u16* Bsrc0 = Bw + (size_t)(tileN + (t >> 2)) * 1024 + scol;
    const u16* Bsrc1 = Bsrc0 + (size_t)64 * 1024;

    const int swzq = (quad ^ ((lr >> 1) & 3)) * 8;
    const int aoff = (wm * 64 + lr) * 32 + swzq;    // + mi*512
    const int boff = (wn * 64 + lr) * 32 + swzq;    // + ni*512

    f32x4 acc[4][4] = {};

#define STAGE_A(tk, buf)                                                        \
    do { GLDS16(Asrc0 + (tk) * 32, &lds[buf][0][t * 8]);                        \
         GLDS16(Asrc1 + (tk) * 32, &lds[buf][0][(t + 256) * 8]); } while (0)
#define STAGE_B(tk, buf)                                                        \
    do { GLDS16(Bsrc0 + (tk) * 32, &lds[buf][1][t * 8]);                        \
         GLDS16(Bsrc1 + (tk) * 32, &lds[buf][1][(t + 256) * 8]); } while (0)

#define DO_TILE(tk, DO_ST, VMASM)                                               \
    do {                                                                        \
        const int cur_ = (tk) & 3, nxt_ = ((tk) + 3) & 3;                       \
        const u16* aL = &lds[cur_][0][0];                                       \
        const u16* bL = &lds[cur_][1][0];                                       \
        if (DO_ST) { STAGE_A((tk) + 3, nxt_); STAGE_B((tk) + 3, nxt_); }        \
        u16x8 af[4], bf[4];                                                     \
        _Pragma("unroll") for (int i = 0; i < 4; ++i)                           \
            af[i] = *(const u16x8*)(aL + aoff + i * 512);                       \
        _Pragma("unroll") for (int i = 0; i < 4; ++i)                           \
            bf[i] = *(const u16x8*)(bL + boff + i * 512);                       \
        __builtin_amdgcn_s_setprio(1);                                          \
        _Pragma("unroll") for (int mi = 0; mi < 4; ++mi)                        \
            _Pragma("unroll") for (int ni = 0; ni < 4; ++ni)                    \
                acc[mi][ni] = mfma16(af[mi], bf[ni], acc[mi][ni]);              \
        __builtin_amdgcn_s_setprio(0);                                          \
        VMASM;                                                                  \
        __builtin_amdgcn_s_barrier();                                           \
    } while (0)

    STAGE_A(0, 0); STAGE_B(0, 0);
    STAGE_A(1, 1); STAGE_B(1, 1);
    STAGE_A(2, 2); STAGE_B(2, 2);
    asm volatile("s_waitcnt vmcnt(8)" ::: "memory");
    __builtin_amdgcn_s_barrier();

#pragma unroll 4
    for (int tk = 0; tk < 28; ++tk)
        DO_TILE(tk, true, asm volatile("s_waitcnt vmcnt(8)" ::: "memory"));
    DO_TILE(28, true,  asm volatile("s_waitcnt vmcnt(8)" ::: "memory"));
    DO_TILE(29, false, asm volatile("s_waitcnt vmcnt(4)" ::: "memory"));
    DO_TILE(30, false, asm volatile("s_waitcnt vmcnt(0)" ::: "memory"));
    DO_TILE(31, false, (void)0);
#undef DO_TILE
#undef STAGE_A
#undef STAGE_B

    // MODE-1 epilogue: fp32 + bias, coalesced (lanes 0-15 contiguous in n).
#pragma unroll
    for (int mi = 0; mi < 4; ++mi)
#pragma unroll
        for (int ni = 0; ni < 4; ++ni) {
            int n = tileN + wn * 64 + ni * 16 + lr;
            float bv = biasp[n];
#pragma unroll
            for (int r = 0; r < 4; ++r) {
                int m = tileM + wm * 64 + mi * 16 + quad * 4 + r;
                Cf[(size_t)m * 1024 + n] = acc[mi][ni][r] + bv;
            }
        }
}

// ---------------- attention: flash-style, 2 q-groups per block (R4) ----------
__global__ __launch_bounds__(256, 2) void attn_kernel(
    const u16* __restrict__ qfm, const u16* __restrict__ k1fm,
    const u16* __restrict__ k2fm, const u16* __restrict__ vfm,
    const int* __restrict__ maskp, const int* __restrict__ qmaskp,
    const float* __restrict__ shiftp, const float* __restrict__ biasp,
    u16* __restrict__ ao)
{
    __shared__ u16 Ks[2][2][2][2][512];  // [buf][kv][t01][kh][lane*8]  16 KB
    __shared__ u16 Vs[2][4][512];        // [buf][ot][lane*8]            8 KB
    __shared__ u16 Pw[4][2][512];        // [wave][group][...]           8 KB

    const int bh = blockIdx.x & 127, qh = blockIdx.x >> 7;
    const int b = bh >> 4;
    const int t = threadIdx.x, lane = t & 63, w = t >> 6;
    const int lr = lane & 15, quad = lane >> 4;
    const float shiftv = shiftp[0], biasv = biasp[0];

    const int m16a = qh * 8 + w;         // group a 16-row q block
    const int m16b = m16a + 4;           // group b
    const int qbaseA = m16a * 16;
    const int qbaseB = m16b * 16;

    const u16* qsrcA = qfm + ((size_t)(bh * 32 + m16a) * 2) * 512 + lane * 8;
    const u16* qsrcB = qfm + ((size_t)(bh * 32 + m16b) * 2) * 512 + lane * 8;
    u16x8 qa0 = *(const u16x8*)(qsrcA);
    u16x8 qa1 = *(const u16x8*)(qsrcA + 512);
    u16x8 qb0 = *(const u16x8*)(qsrcB);
    u16x8 qb1 = *(const u16x8*)(qsrcB + 512);

    int qmrA[4], qmrB[4]; float rowfA[4], rowfB[4];
#pragma unroll
    for (int r = 0; r < 4; ++r) {
        int ma = qbaseA + quad * 4 + r;
        int mb = qbaseB + quad * 4 + r;
        qmrA[r] = qmaskp[b * 512 + ma];
        qmrB[r] = qmaskp[b * 512 + mb];
        rowfA[r] = (float)ma;
        rowfB[r] = (float)mb;
    }

    f32x4 oa0 = {0,0,0,0}, oa1 = {0,0,0,0}, oa2 = {0,0,0,0}, oa3 = {0,0,0,0};
    f32x4 ob0 = {0,0,0,0}, ob1 = {0,0,0,0}, ob2 = {0,0,0,0}, ob3 = {0,0,0,0};
    float lsa[4] = {0,0,0,0}, lsb[4] = {0,0,0,0};

    u16* pbA = &Pw[w][0][0];
    u16* pbB = &Pw[w][1][0];
    const int wa0 = quad * 128 + (((lr >> 3) ^ quad) * 8) + (lr & 7);
    const int wa1 = quad * 128 + (((2 | (lr >> 3)) ^ quad) * 8) + (lr & 7);
    const int ra = lr * 32 + ((quad ^ (lr >> 2)) * 8);

    const int s_ = w >> 1, kh_ = w & 1;
    const u16* k1s = k1fm + ((size_t)(bh * 32 + s_) * 2 + kh_) * 512 + lane * 8;
    const u16* k2s = k2fm + ((size_t)(bh * 32 + s_) * 2 + kh_) * 512 + lane * 8;
    const u16* vsrc = vfm + ((size_t)(bh * 4 + w) * 16) * 512 + lane * 8;

#define ASTAGE(cc, bufi)                                                        \
    do {                                                                        \
        GLDS16(k1s + (size_t)(cc) * 2048, &Ks[bufi][0][s_][kh_][lane * 8]);     \
        GLDS16(k2s + (size_t)(cc) * 2048, &Ks[bufi][1][s_][kh_][lane * 8]);     \
        GLDS16(vsrc + (size_t)(cc) * 512, &Vs[bufi][w][lane * 8]);              \
    } while (0)

    const int* qmb = qmaskp + b * 512;
    const int* kmb = maskp + b * 512;

    ASTAGE(0, 0);
    __syncthreads();

    for (int cc = 0; cc < 16; ++cc) {
        const int cur = cc & 1;
        if (cc < 15) ASTAGE(cc + 1, cur ^ 1);

        u16x8 k1t0a = *(const u16x8*)(&Ks[cur][0][0][0][lane * 8]);
        u16x8 k1t0b = *(const u16x8*)(&Ks[cur][0][0][1][lane * 8]);
        u16x8 k1t1a = *(const u16x8*)(&Ks[cur][0][1][0][lane * 8]);
        u16x8 k1t1b = *(const u16x8*)(&Ks[cur][0][1][1][lane * 8]);
        u16x8 k2t0a = *(const u16x8*)(&Ks[cur][1][0][0][lane * 8]);
        u16x8 k2t0b = *(const u16x8*)(&Ks[cur][1][0][1][lane * 8]);
        u16x8 k2t1a = *(const u16x8*)(&Ks[cur][1][1][0][lane * 8]);
        u16x8 k2t1b = *(const u16x8*)(&Ks[cur][1][1][1][lane * 8]);

        f32x4 z = {0.f, 0.f, 0.f, 0.f};
        f32x4 sa1t0 = mfma16(qa1, k1t0b, mfma16(qa0, k1t0a, z));
        f32x4 sa2t0 = mfma16(qa1, k2t0b, mfma16(qa0, k2t0a, z));
        f32x4 sa1t1 = mfma16(qa1, k1t1b, mfma16(qa0, k1t1a, z));
        f32x4 sa2t1 = mfma16(qa1, k2t1b, mfma16(qa0, k2t1a, z));
        f32x4 sb1t0 = mfma16(qb1, k1t0b, mfma16(qb0, k1t0a, z));
        f32x4 sb2t0 = mfma16(qb1, k2t0b, mfma16(qb0, k2t0a, z));
        f32x4 sb1t1 = mfma16(qb1, k1t1b, mfma16(qb0, k1t1a, z));
        f32x4 sb2t1 = mfma16(qb1, k2t1b, mfma16(qb0, k2t1a, z));

        const int col0 = cc * 32 + lr, col1 = col0 + 16;
        const int qmc0 = qmb[col0], qmc1 = qmb[col1];
        const float ka0 = (kmb[col0] ? 0.f : -1e30f) - 10.0f;
        const float ka1 = (kmb[col1] ? 0.f : -1e30f) - 10.0f;
        const float colf0 = (float)col0, colf1 = (float)col1;

        u16x8 vf0 = *(const u16x8*)(&Vs[cur][0][lane * 8]);
        u16x8 vf1 = *(const u16x8*)(&Vs[cur][1][lane * 8]);
        u16x8 vf2 = *(const u16x8*)(&Vs[cur][2][lane * 8]);
        u16x8 vf3 = *(const u16x8*)(&Vs[cur][3][lane * 8]);

        {
            float p0[4], p1[4];
#pragma unroll
            for (int r = 0; r < 4; ++r) {
                float d0 = rowfA[r] - colf0;
                float d1 = rowfA[r] - colf1;
                float sel0 = (qmrA[r] == qmc0) ? sa1t0[r] : sa2t0[r];
                float sel1 = (qmrA[r] == qmc1) ? sa1t1[r] : sa2t1[r];
                float v0 = fmaf(sel0, 0.125f, -fmaf(shiftv * d0, d0, biasv)) + ka0;
                float v1 = fmaf(sel1, 0.125f, -fmaf(shiftv * d1, d1, biasv)) + ka1;
                p0[r] = __expf(v0);
                p1[r] = __expf(v1);
                lsa[r] += p0[r] + p1[r];
            }
#pragma unroll
            for (int r = 0; r < 4; ++r) {
                pbA[wa0 + r * 32] = f2b(p0[r]);
                pbA[wa1 + r * 32] = f2b(p1[r]);
            }
            u16x8 af = *(const u16x8*)(pbA + ra);   // same-wave RAW; lgkmcnt only
            oa0 = mfma16(af, vf0, oa0);
            oa1 = mfma16(af, vf1, oa1);
            oa2 = mfma16(af, vf2, oa2);
            oa3 = mfma16(af, vf3, oa3);
        }
        {
            float p0[4], p1[4];
#pragma unroll
            for (int r = 0; r < 4; ++r) {
                float d0 = rowfB[r] - colf0;
                float d1 = rowfB[r] - colf1;
                float sel0 = (qmrB[r] == qmc0) ? sb1t0[r] : sb2t0[r];
                float sel1 = (qmrB[r] == qmc1) ? sb1t1[r] : sb2t1[r];
                float v0 = fmaf(sel0, 0.125f, -fmaf(shiftv * d0, d0, biasv)) + ka0;
                float v1 = fmaf(sel1, 0.125f, -fmaf(shiftv * d1, d1, biasv)) + ka1;
                p0[r] = __expf(v0);
                p1[r] = __expf(v1);
                lsb[r] += p0[r] + p1[r];
            }
#pragma unroll
            for (int r = 0; r < 4; ++r) {
                pbB[wa0 + r * 32] = f2b(p0[r]);
                pbB[wa1 + r * 32] = f2b(p1[r]);
            }
            u16x8 af = *(const u16x8*)(pbB + ra);
            ob0 = mfma16(af, vf0, ob0);
            ob1 = mfma16(af, vf1, ob1);
            ob2 = mfma16(af, vf2, ob2);
            ob3 = mfma16(af, vf3, ob3);
        }

        __syncthreads();
    }
#undef ASTAGE

#pragma unroll
    for (int r = 0; r < 4; ++r) {
        float s = lsa[r];
#pragma unroll
        for (int m = 1; m < 16; m <<= 1) s += __shfl_xor(s, m);
        float inv = 1.0f / s;
        int grow = b * 512 + qbaseA + quad * 4 + r;
        u16* orow = ao + (size_t)grow * 1024 + (bh & 15) * 64 + lr;
        orow[0]  = f2b(oa0[r] * inv);
        orow[16] = f2b(oa1[r] * inv);
        orow[32] = f2b(oa2[r] * inv);
        orow[48] = f2b(oa3[r] * inv);
    }
#pragma unroll
    for (int r = 0; r < 4; ++r) {
        float s = lsb[r];
#pragma unroll
        for (int m = 1; m < 16; m <<= 1) s += __shfl_xor(s, m);
        float inv = 1.0f / s;
        int grow = b * 512 + qbaseB + quad * 4 + r;
        u16* orow = ao + (size_t)grow * 1024 + (bh & 15) * 64 + lr;
        orow[0]  = f2b(ob0[r] * inv);
        orow[16] = f2b(ob1[r] * inv);
        orow[32] = f2b(ob2[r] * inv);
        orow[48] = f2b(ob3[r] * inv);
    }
}

extern "C" void kernel_launch(void* const* d_in, const int* in_sizes, int n_in,
                              void* d_out, int out_size, void* d_ws, size_t ws_size,
                              hipStream_t stream) {
    (void)in_sizes; (void)n_in; (void)out_size; (void)ws_size;
    const float* x      = (const float*)d_in[0];
    const int*   maskp  = (const int*)d_in[1];
    const int*   qmaskp = (const int*)d_in[2];
    const float* Wqkv   = (const float*)d_in[3];
    const float* fc_w   = (const float*)d_in[4];
    const float* fc_b   = (const float*)d_in[5];
    const float* shiftp = (const float*)d_in[6];
    const float* biasp  = (const float*)d_in[7];
    float* out = (float*)d_out;

    char* ws = (char*)d_ws;
    u16* xb   = (u16*)(ws);                      //  8 MB: x bf16 [4096,1024]
    u16* wb   = (u16*)(ws + (8u << 20));         //  8 MB: Wqkv bf16 [4096,1024]
    u16* fwb  = (u16*)(ws + (16u << 20));        //  2 MB: fc_w bf16 [1024,1024]
    u16* qfm  = (u16*)(ws + (18u << 20));        //  8 MB: q frag-major
    u16* k1fm = (u16*)(ws + (26u << 20));        //  8 MB: k1 frag-major
    u16* k2fm = (u16*)(ws + (34u << 20));        //  8 MB: k2 frag-major
    u16* vfm  = (u16*)(ws + (42u << 20));        //  8 MB: v frag-major
    u16* aob  = (u16*)(ws + (50u << 20));        //  8 MB: attn out bf16 [4096,1024]

    cvt3_kernel<<<9216, 256, 0, stream>>>(x, Wqkv, fc_w, xb, wb, fwb);
    gemm256_qkv<<<256, 512, 0, stream>>>(xb, wb, qfm, k1fm, k2fm, vfm);
    attn_kernel<<<512, 256, 0, stream>>>(qfm, k1fm, k2fm, vfm, maskp, qmaskp,
                                         shiftp, biasp, aob);
    gemm128_proj<<<256, 256, 0, stream>>>(aob, fwb, out, fc_b);
}